// Round 5
// baseline (955.519 us; speedup 1.0000x reference)
//
#include <hip/hip_runtime.h>
#include <hip/hip_bf16.h>
#include <math.h>

#define B_TOK 8192
#define DDIM  1024
#define HDIM  4096
#define NEXP  8
#define CAP   18432   // 16384 routed pairs + 8*255 padding (256-tile), rounded up

typedef unsigned short u16;
using f32x4  = __attribute__((ext_vector_type(4))) float;
using bf16x8 = __attribute__((ext_vector_type(8))) short;  // 8 bf16 in 4 VGPRs

__device__ __forceinline__ u16 f2bf(float f) {
  union { float f; unsigned u; } v; v.f = f;
  unsigned r = v.u + 0x7FFFu + ((v.u >> 16) & 1u);  // RNE
  return (u16)(r >> 16);
}

__device__ __forceinline__ void load_lds16(const void* g, void* l) {
  __builtin_amdgcn_global_load_lds((const __attribute__((address_space(1))) void*)g,
                                   (__attribute__((address_space(3))) void*)l,
                                   16, 0, 0);
}

// ---------------- f32 -> bf16 conversion (vectorized) ----------------
__global__ __launch_bounds__(256) void cvt_kernel(const float4* __restrict__ src,
                                                  ushort4* __restrict__ dst, int n4) {
  for (int i = blockIdx.x * 256 + threadIdx.x; i < n4; i += gridDim.x * 256) {
    float4 v = src[i];
    ushort4 o;
    o.x = f2bf(v.x); o.y = f2bf(v.y); o.z = f2bf(v.z); o.w = f2bf(v.w);
    dst[i] = o;
  }
}

// ---------------- gating: logits (f64 accum), top-2, softmax ----------------
__global__ __launch_bounds__(256) void gate_kernel(
    const float* __restrict__ inp, const float* __restrict__ gw,
    const float* __restrict__ gb, int* __restrict__ tok_e,
    float* __restrict__ tok_g, int* __restrict__ counts)
{
  int gtid = blockIdx.x * 256 + threadIdx.x;
  int tok  = gtid >> 6;
  int lane = threadIdx.x & 63;
  if (tok >= B_TOK) return;
  const float4* X = (const float4*)(inp + (size_t)tok * DDIM);
  float4 x[4];
#pragma unroll
  for (int j = 0; j < 4; ++j) x[j] = X[j * 64 + lane];
  float lg[NEXP];
#pragma unroll
  for (int e = 0; e < NEXP; ++e) {
    const float4* W = (const float4*)(gw + e * DDIM);
    double s = 0.0;
#pragma unroll
    for (int j = 0; j < 4; ++j) {
      float4 w = W[j * 64 + lane];
      s += (double)x[j].x * w.x + (double)x[j].y * w.y
         + (double)x[j].z * w.z + (double)x[j].w * w.w;
    }
#pragma unroll
    for (int o = 32; o > 0; o >>= 1) s += __shfl_xor(s, o);
    lg[e] = (float)(s + (double)gb[e]);
  }
  if (lane == 0) {
    int i0 = 0; float v0 = lg[0];
#pragma unroll
    for (int e = 1; e < NEXP; ++e) if (lg[e] > v0) { v0 = lg[e]; i0 = e; }
    int i1 = -1; float v1 = -3.4e38f;
#pragma unroll
    for (int e = 0; e < NEXP; ++e) if (e != i0 && lg[e] > v1) { v1 = lg[e]; i1 = e; }
    float t   = __expf(v1 - v0);
    float inv = 1.0f / (1.0f + t);
    tok_e[2 * tok] = i0; tok_e[2 * tok + 1] = i1;
    tok_g[2 * tok] = inv; tok_g[2 * tok + 1] = t * inv;
    atomicAdd(&counts[i0], 1);
    atomicAdd(&counts[i1], 1);
  }
}

// ---------------- offsets (pad each expert to 256) ----------------
__global__ void scan_kernel(const int* __restrict__ counts, int* __restrict__ offs,
                            int* __restrict__ padded)
{
  if (threadIdx.x == 0 && blockIdx.x == 0) {
    int off = 0;
    for (int e = 0; e < NEXP; ++e) {
      offs[e] = off;
      int p = (counts[e] + 255) & ~255;
      padded[e] = p;
      off += p;
    }
  }
}

// ---------------- scatter tokens into expert slots ----------------
__global__ __launch_bounds__(256) void scatter_kernel(
    const int* __restrict__ tok_e, const float* __restrict__ tok_g,
    const int* __restrict__ offs, int* __restrict__ cursors,
    int* __restrict__ slot_token, float* __restrict__ slot_gate)
{
  int b = blockIdx.x * 256 + threadIdx.x;
  if (b >= B_TOK) return;
#pragma unroll
  for (int k = 0; k < 2; ++k) {
    int e   = tok_e[2 * b + k];
    float g = tok_g[2 * b + k];
    int pos = atomicAdd(&cursors[e], 1);
    int s   = offs[e] + pos;
    slot_token[s] = b;
    slot_gate[s]  = g;
  }
}

// ================== 256x256x64 8-phase GEMM template pieces ==================
// LDS per matrix per buf: [256 rows][64 cols] bf16, 16B-slot XOR swizzle:
//   phys_slot = logical_slot ^ (row & 7).  Stage keeps LDS linear and
//   pre-swizzles the GLOBAL source column chunk; ds_read XORs the slot.

#define STG_A(bf_, hh_, kt_) do {                                         \
    load_lds16(pA[hh_][0] + (kt_) * 64, &As[bf_][(hh_)*8192 + sdst]);      \
    load_lds16(pA[hh_][1] + (kt_) * 64, &As[bf_][(hh_)*8192 + 4096 + sdst]); } while (0)
#define STG_B(bf_, hh_, kt_) do {                                         \
    load_lds16(pB[hh_][0] + (kt_) * 64, &Bs[bf_][(hh_)*8192 + sdst]);      \
    load_lds16(pB[hh_][1] + (kt_) * 64, &Bs[bf_][(hh_)*8192 + 4096 + sdst]); } while (0)

#define LDA_Q(bf_, mh_) do {                                              \
  _Pragma("unroll") for (int mf = 0; mf < 4; ++mf)                        \
    _Pragma("unroll") for (int ks = 0; ks < 2; ++ks)                      \
      af[mf][ks] = *(const bf16x8*)&As[bf_][(a_rb + (mh_)*64 + mf*16)*64  \
                                           + ((ks*4 + fq) ^ fr7)*8]; } while (0)
#define LDB_Q(bf_, nh_) do {                                              \
  _Pragma("unroll") for (int nf = 0; nf < 2; ++nf)                        \
    _Pragma("unroll") for (int ks = 0; ks < 2; ++ks)                      \
      bfr[(nh_)*2+nf][ks] = *(const bf16x8*)&Bs[bf_][(b_rb + (nh_)*32 + nf*16)*64 \
                                           + ((ks*4 + fq) ^ fr7)*8]; } while (0)
#define MFMA_Q(mh_, nh_) do {                                             \
  _Pragma("unroll") for (int ks = 0; ks < 2; ++ks)                        \
  _Pragma("unroll") for (int mf = 0; mf < 4; ++mf)                        \
  _Pragma("unroll") for (int nf = 0; nf < 2; ++nf)                        \
    acc[(mh_)*4+mf][(nh_)*2+nf] = __builtin_amdgcn_mfma_f32_16x16x32_bf16( \
        af[mf][ks], bfr[(nh_)*2+nf][ks], acc[(mh_)*4+mf][(nh_)*2+nf], 0, 0, 0); } while (0)

#define PH_MID do { __builtin_amdgcn_s_barrier();                         \
    asm volatile("s_waitcnt lgkmcnt(0)" ::: "memory");                    \
    __builtin_amdgcn_sched_barrier(0); } while (0)
#define PH_END do { __builtin_amdgcn_s_barrier();                         \
    __builtin_amdgcn_sched_barrier(0); } while (0)
#define VMW(n_) asm volatile("s_waitcnt vmcnt(" #n_ ")" ::: "memory")
#define P1 __builtin_amdgcn_s_setprio(1)
#define P0 __builtin_amdgcn_s_setprio(0)

// One full 8-phase double-K-tile iteration. buf0 holds even tiles, buf1 odd.
#define GEMM_ITER(NI_) do {                                               \
    const int t1 = 2 * i + 1;                                             \
    const bool more = (i + 1 < (NI_));                                    \
    /* j0 */ LDA_Q(0, 0); LDB_Q(0, 0); STG_A(1, 1, t1);                   \
    PH_MID; P1; MFMA_Q(0, 0); P0; PH_END;                                 \
    /* j1 */ LDB_Q(0, 1); STG_B(1, 0, t1);                                \
    PH_MID; P1; MFMA_Q(0, 1); P0; PH_END;                                 \
    /* j2 */ LDA_Q(0, 1); STG_B(1, 1, t1);                                \
    PH_MID; P1; MFMA_Q(1, 0); P0; PH_END;                                 \
    /* j3 */ if (more) STG_A(0, 0, t1 + 1);                               \
    PH_MID; P1; MFMA_Q(1, 1); P0;                                         \
    if (more) { VMW(2); } else { VMW(0); }                                \
    PH_END;                                                               \
    /* j4 */ LDA_Q(1, 0); LDB_Q(1, 0); if (more) STG_A(0, 1, t1 + 1);     \
    PH_MID; P1; MFMA_Q(0, 0); P0; PH_END;                                 \
    /* j5 */ LDB_Q(1, 1); if (more) STG_B(0, 0, t1 + 1);                  \
    PH_MID; P1; MFMA_Q(0, 1); P0; PH_END;                                 \
    /* j6 */ LDA_Q(1, 1); if (more) STG_B(0, 1, t1 + 1);                  \
    PH_MID; P1; MFMA_Q(1, 0); P0; PH_END;                                 \
    /* j7 */ if (more) STG_A(1, 0, t1 + 2);                               \
    PH_MID; P1; MFMA_Q(1, 1); P0;                                         \
    VMW(2);                                                               \
    PH_END;                                                               \
  } while (0)

// ---------------- GEMM1: h = relu(X_gather @ W1[e]^T + b1[e]) -> bf16 ----------------
__global__ __launch_bounds__(512, 2) void gemm1_kernel(
    const u16* __restrict__ Xb, const u16* __restrict__ W1b,
    const float* __restrict__ b1, const int* __restrict__ slot_token,
    const int* __restrict__ offs, const int* __restrict__ padded,
    u16* __restrict__ Hb)
{
  const int h   = blockIdx.x + 16 * (blockIdx.y + 32 * blockIdx.z);  // grid (16,32,8)
  const int e   = h & 7;          // XCD id == expert
  const int r   = h >> 3;
  const int mi  = r >> 4;         // m-tile [0,32)
  const int nti = r & 15;         // n-tile fastest within XCD
  if (mi * 256 >= padded[e]) return;
  const int base_slot = offs[e] + mi * 256;
  const int n0 = nti * 256;
  const int NKT = DDIM / 64;      // 16
  const int NI  = NKT / 2;        // 8

  __shared__ __align__(16) u16 As[2][16384];
  __shared__ __align__(16) u16 Bs[2][16384];
  __shared__ int toks[256];

  const int tid = threadIdx.x;
  if (tid < 256) toks[tid] = slot_token[base_slot + tid];
  __syncthreads();

  // staging setup (pre-swizzled global source column chunk)
  const int srow = tid >> 3;
  const int scol = ((tid & 7) ^ (srow & 7)) * 8;
  const int sdst = tid * 8;
  const u16* pA[2][2];
  const u16* pB[2][2];
#pragma unroll
  for (int hh = 0; hh < 2; ++hh)
#pragma unroll
    for (int g = 0; g < 2; ++g) {
      int rr = hh * 128 + g * 64 + srow;
      pA[hh][g] = Xb + (size_t)toks[rr] * DDIM + scol;
      pB[hh][g] = W1b + ((size_t)e * HDIM + (size_t)(n0 + rr)) * DDIM + scol;
    }

  const int wid = tid >> 6, lane = tid & 63;
  const int wr = wid >> 2, wc = wid & 3;
  const int fr = lane & 15, fq = lane >> 4, fr7 = fr & 7;
  const int a_rb = wr * 128 + fr;
  const int b_rb = wc * 64 + fr;

  f32x4 acc[8][4];
#pragma unroll
  for (int m = 0; m < 8; ++m)
#pragma unroll
    for (int n = 0; n < 4; ++n) acc[m][n] = f32x4{0.f, 0.f, 0.f, 0.f};
  bf16x8 af[4][2], bfr[4][2];

  // prologue: tile0 all halves + tile1 A-h0
  STG_A(0, 0, 0); STG_A(0, 1, 0); STG_B(0, 0, 0); STG_B(0, 1, 0);
  STG_A(1, 0, 1);
  VMW(2);
  PH_END;

#pragma unroll 1
  for (int i = 0; i < NI; ++i) GEMM_ITER(NI);

  // epilogue: bias + relu -> bf16
#pragma unroll
  for (int nf = 0; nf < 4; ++nf) {
    const int col = n0 + wc * 64 + nf * 16 + fr;
    const float bias = b1[e * HDIM + col];
#pragma unroll
    for (int mf = 0; mf < 8; ++mf) {
      const int row0 = wr * 128 + mf * 16 + fq * 4;
#pragma unroll
      for (int j = 0; j < 4; ++j) {
        float v = acc[mf][nf][j] + bias;
        v = v > 0.f ? v : 0.f;
        Hb[(size_t)(base_slot + row0 + j) * HDIM + col] = f2bf(v);
      }
    }
  }
}

// ---------------- GEMM2: p = gate*exp(relu(H @ W2[e]^T + b2[e])), atomic add ----------------
__global__ __launch_bounds__(512, 2) void gemm2_kernel(
    const u16* __restrict__ Hb, const u16* __restrict__ W2b,
    const float* __restrict__ b2, const float* __restrict__ slot_gate,
    const int* __restrict__ slot_token, const int* __restrict__ offs,
    const int* __restrict__ padded, float* __restrict__ out)
{
  const int h   = blockIdx.x + 4 * (blockIdx.y + 32 * blockIdx.z);  // grid (4,32,8)
  const int e   = h & 7;
  const int r   = h >> 3;
  const int mi  = r >> 2;         // m-tile [0,32)
  const int nti = r & 3;          // n-tile fastest within XCD
  if (mi * 256 >= padded[e]) return;
  const int base_slot = offs[e] + mi * 256;
  const int n0 = nti * 256;
  const int NKT = HDIM / 64;      // 64
  const int NI  = NKT / 2;        // 32

  __shared__ __align__(16) u16 As[2][16384];
  __shared__ __align__(16) u16 Bs[2][16384];
  __shared__ int   toks[256];
  __shared__ float gts[256];

  const int tid = threadIdx.x;
  if (tid < 256) {
    toks[tid] = slot_token[base_slot + tid];
    gts[tid]  = slot_gate[base_slot + tid];
  }
  __syncthreads();

  const int srow = tid >> 3;
  const int scol = ((tid & 7) ^ (srow & 7)) * 8;
  const int sdst = tid * 8;
  const u16* pA[2][2];
  const u16* pB[2][2];
#pragma unroll
  for (int hh = 0; hh < 2; ++hh)
#pragma unroll
    for (int g = 0; g < 2; ++g) {
      int rr = hh * 128 + g * 64 + srow;
      pA[hh][g] = Hb + (size_t)(base_slot + rr) * HDIM + scol;
      pB[hh][g] = W2b + ((size_t)e * DDIM + (size_t)(n0 + rr)) * HDIM + scol;
    }

  const int wid = tid >> 6, lane = tid & 63;
  const int wr = wid >> 2, wc = wid & 3;
  const int fr = lane & 15, fq = lane >> 4, fr7 = fr & 7;
  const int a_rb = wr * 128 + fr;
  const int b_rb = wc * 64 + fr;

  f32x4 acc[8][4];
#pragma unroll
  for (int m = 0; m < 8; ++m)
#pragma unroll
    for (int n = 0; n < 4; ++n) acc[m][n] = f32x4{0.f, 0.f, 0.f, 0.f};
  bf16x8 af[4][2], bfr[4][2];

  STG_A(0, 0, 0); STG_A(0, 1, 0); STG_B(0, 0, 0); STG_B(0, 1, 0);
  STG_A(1, 0, 1);
  VMW(2);
  PH_END;

#pragma unroll 1
  for (int i = 0; i < NI; ++i) GEMM_ITER(NI);

  // epilogue: bias + relu -> gate*exp -> atomic add
#pragma unroll
  for (int nf = 0; nf < 4; ++nf) {
    const int col = n0 + wc * 64 + nf * 16 + fr;
    const float bias = b2[e * DDIM + col];
#pragma unroll
    for (int mf = 0; mf < 8; ++mf) {
      const int row0 = wr * 128 + mf * 16 + fq * 4;
#pragma unroll
      for (int j = 0; j < 4; ++j) {
        const int row = row0 + j;
        float v = acc[mf][nf][j] + bias;
        v = v > 0.f ? v : 0.f;
        float p = gts[row] * __expf(v);
        atomicAdd(&out[(size_t)toks[row] * DDIM + col], p);
      }
    }
  }
}

// ---------------- final: out = log(out + eps), in place ----------------
__global__ __launch_bounds__(256) void log_kernel(float4* __restrict__ out, int n4) {
  const float EPS = 2.220446049250313e-16f;
  for (int i = blockIdx.x * 256 + threadIdx.x; i < n4; i += gridDim.x * 256) {
    float4 v = out[i];
    v.x = logf(v.x + EPS);
    v.y = logf(v.y + EPS);
    v.z = logf(v.z + EPS);
    v.w = logf(v.w + EPS);
    out[i] = v;
  }
}

extern "C" void kernel_launch(void* const* d_in, const int* in_sizes, int n_in,
                              void* d_out, int out_size, void* d_ws, size_t ws_size,
                              hipStream_t stream)
{
  const float* inp = (const float*)d_in[0];
  const float* gw  = (const float*)d_in[1];
  const float* gb  = (const float*)d_in[2];
  const float* W1  = (const float*)d_in[3];
  const float* b1  = (const float*)d_in[4];
  const float* W2  = (const float*)d_in[5];
  const float* b2  = (const float*)d_in[6];
  float* out = (float*)d_out;

  char* ws = (char*)d_ws;
  size_t off = 0;
  auto alloc = [&](size_t bytes) {
    void* p = ws + off;
    off = (off + bytes + 255) & ~(size_t)255;
    return p;
  };
  u16*   Xb  = (u16*)alloc((size_t)B_TOK * DDIM * 2);
  u16*   W1b = (u16*)alloc((size_t)NEXP * HDIM * DDIM * 2);
  u16*   W2b = (u16*)alloc((size_t)NEXP * DDIM * HDIM * 2);
  u16*   Hb  = (u16*)alloc((size_t)CAP * HDIM * 2);
  int*   slot_token = (int*)alloc(CAP * 4);
  float* slot_gate  = (float*)alloc(CAP * 4);
  int*   tok_e = (int*)alloc(B_TOK * 2 * 4);
  float* tok_g = (float*)alloc(B_TOK * 2 * 4);
  int*   counts  = (int*)alloc(32);
  int*   offs    = (int*)alloc(32);
  int*   padded  = (int*)alloc(32);
  int*   cursors = (int*)alloc(32);

  (void)hipMemsetAsync(counts, 0, 32, stream);
  (void)hipMemsetAsync(cursors, 0, 32, stream);
  (void)hipMemsetAsync(slot_token, 0, CAP * 4, stream);
  (void)hipMemsetAsync(slot_gate, 0, CAP * 4, stream);
  (void)hipMemsetAsync(out, 0, (size_t)out_size * 4, stream);

  cvt_kernel<<<2048, 256, 0, stream>>>((const float4*)inp, (ushort4*)Xb, B_TOK * DDIM / 4);
  cvt_kernel<<<2048, 256, 0, stream>>>((const float4*)W1, (ushort4*)W1b, NEXP * HDIM * DDIM / 4);
  cvt_kernel<<<2048, 256, 0, stream>>>((const float4*)W2, (ushort4*)W2b, NEXP * DDIM * HDIM / 4);

  gate_kernel<<<B_TOK / 4, 256, 0, stream>>>(inp, gw, gb, tok_e, tok_g, counts);
  scan_kernel<<<1, 64, 0, stream>>>(counts, offs, padded);
  scatter_kernel<<<B_TOK / 256, 256, 0, stream>>>(tok_e, tok_g, offs, cursors,
                                                  slot_token, slot_gate);

  gemm1_kernel<<<dim3(16, 32, NEXP), 512, 0, stream>>>(
      Xb, W1b, b1, slot_token, offs, padded, Hb);
  gemm2_kernel<<<dim3(4, 32, NEXP), 512, 0, stream>>>(
      Hb, W2b, b2, slot_gate, slot_token, offs, padded, out);

  log_kernel<<<2048, 256, 0, stream>>>((float4*)out, out_size / 4);
}

// Round 6
// 840.813 us; speedup vs baseline: 1.1364x; 1.1364x over previous
//
#include <hip/hip_runtime.h>
#include <hip/hip_bf16.h>
#include <math.h>

#define B_TOK 8192
#define DDIM  1024
#define HDIM  4096
#define NEXP  8
#define CAP   17408   // 16384 routed pairs + 8*127 padding (128-tile)

typedef unsigned short u16;
using f32x4  = __attribute__((ext_vector_type(4))) float;
using bf16x8 = __attribute__((ext_vector_type(8))) short;  // 8 bf16 in 4 VGPRs

__device__ __forceinline__ u16 f2bf(float f) {
  union { float f; unsigned u; } v; v.f = f;
  unsigned r = v.u + 0x7FFFu + ((v.u >> 16) & 1u);  // RNE
  return (u16)(r >> 16);
}

__device__ __forceinline__ void load_lds16(const void* g, void* l) {
  __builtin_amdgcn_global_load_lds((const __attribute__((address_space(1))) void*)g,
                                   (__attribute__((address_space(3))) void*)l,
                                   16, 0, 0);
}

// ---------------- f32 -> bf16 conversion (vectorized) ----------------
__global__ __launch_bounds__(256) void cvt_kernel(const float4* __restrict__ src,
                                                  ushort4* __restrict__ dst, int n4) {
  for (int i = blockIdx.x * 256 + threadIdx.x; i < n4; i += gridDim.x * 256) {
    float4 v = src[i];
    ushort4 o;
    o.x = f2bf(v.x); o.y = f2bf(v.y); o.z = f2bf(v.z); o.w = f2bf(v.w);
    dst[i] = o;
  }
}

// ---------------- gating: logits (f64 accum), top-2, softmax ----------------
__global__ __launch_bounds__(256) void gate_kernel(
    const float* __restrict__ inp, const float* __restrict__ gw,
    const float* __restrict__ gb, int* __restrict__ tok_e,
    float* __restrict__ tok_g, int* __restrict__ counts)
{
  int gtid = blockIdx.x * 256 + threadIdx.x;
  int tok  = gtid >> 6;
  int lane = threadIdx.x & 63;
  if (tok >= B_TOK) return;
  const float4* X = (const float4*)(inp + (size_t)tok * DDIM);
  float4 x[4];
#pragma unroll
  for (int j = 0; j < 4; ++j) x[j] = X[j * 64 + lane];
  float lg[NEXP];
#pragma unroll
  for (int e = 0; e < NEXP; ++e) {
    const float4* W = (const float4*)(gw + e * DDIM);
    double s = 0.0;
#pragma unroll
    for (int j = 0; j < 4; ++j) {
      float4 w = W[j * 64 + lane];
      s += (double)x[j].x * w.x + (double)x[j].y * w.y
         + (double)x[j].z * w.z + (double)x[j].w * w.w;
    }
#pragma unroll
    for (int o = 32; o > 0; o >>= 1) s += __shfl_xor(s, o);
    lg[e] = (float)(s + (double)gb[e]);
  }
  if (lane == 0) {
    int i0 = 0; float v0 = lg[0];
#pragma unroll
    for (int e = 1; e < NEXP; ++e) if (lg[e] > v0) { v0 = lg[e]; i0 = e; }
    int i1 = -1; float v1 = -3.4e38f;
#pragma unroll
    for (int e = 0; e < NEXP; ++e) if (e != i0 && lg[e] > v1) { v1 = lg[e]; i1 = e; }
    float t   = __expf(v1 - v0);
    float inv = 1.0f / (1.0f + t);
    tok_e[2 * tok] = i0; tok_e[2 * tok + 1] = i1;
    tok_g[2 * tok] = inv; tok_g[2 * tok + 1] = t * inv;
    atomicAdd(&counts[i0], 1);
    atomicAdd(&counts[i1], 1);
  }
}

// ---------------- offsets (pad each expert to 128) ----------------
__global__ void scan_kernel(const int* __restrict__ counts, int* __restrict__ offs,
                            int* __restrict__ padded)
{
  if (threadIdx.x == 0 && blockIdx.x == 0) {
    int off = 0;
    for (int e = 0; e < NEXP; ++e) {
      offs[e] = off;
      int p = (counts[e] + 127) & ~127;
      padded[e] = p;
      off += p;
    }
  }
}

// ---------------- scatter tokens into expert slots ----------------
__global__ __launch_bounds__(256) void scatter_kernel(
    const int* __restrict__ tok_e, const float* __restrict__ tok_g,
    const int* __restrict__ offs, int* __restrict__ cursors,
    int* __restrict__ slot_token, float* __restrict__ slot_gate)
{
  int b = blockIdx.x * 256 + threadIdx.x;
  if (b >= B_TOK) return;
#pragma unroll
  for (int k = 0; k < 2; ++k) {
    int e   = tok_e[2 * b + k];
    float g = tok_g[2 * b + k];
    int pos = atomicAdd(&cursors[e], 1);
    int s   = offs[e] + pos;
    slot_token[s] = b;
    slot_gate[s]  = g;
  }
}

// ============= 128x128xBK64 GEMM, XOR-swizzled LDS, 2-buf counted vmcnt =============
// LDS tile per matrix per buf: [128 rows][64 K] bf16 = 128 B/row = 8 x 16B slots.
// Swizzle: phys_slot = logical_slot ^ (row & 7).  Staged via linear-dest
// global_load_lds with PRE-SWIZZLED global source column; ds_read applies the
// same XOR -> conflict-free (uniform 8 lanes per bank-quad).

#define STAGE(bf_, kt_) do {                                              \
    _Pragma("unroll") for (int g = 0; g < 4; ++g) {                       \
      load_lds16(pAg[g] + (kt_) * 64, &As[bf_][g * 2048 + sdst]);          \
      load_lds16(pBg[g] + (kt_) * 64, &Bs[bf_][g * 2048 + sdst]);          \
    } } while (0)

#define VMW(n_) asm volatile("s_waitcnt vmcnt(" #n_ ")" ::: "memory")
#define SBAR __builtin_amdgcn_s_barrier()
#define SCHED0 __builtin_amdgcn_sched_barrier(0)

#define GEMM_BODY(NT_) do {                                               \
  /* prologue: tiles 0,1 */                                               \
  STAGE(0, 0); STAGE(1, 1);                                               \
  VMW(8); SBAR; SCHED0;                                                   \
  _Pragma("unroll 1")                                                     \
  for (int t = 0; t < (NT_); ++t) {                                       \
    const int cur = t & 1;                                                \
    bf16x8 af[4][2], bfr[4][2];                                           \
    _Pragma("unroll") for (int m = 0; m < 4; ++m)                         \
      _Pragma("unroll") for (int kk = 0; kk < 2; ++kk)                    \
        af[m][kk] = *(const bf16x8*)&As[cur][(wm + m*16 + fr)*64          \
                                      + (((kk*4 + fq) ^ fr7) * 8)];       \
    _Pragma("unroll") for (int n = 0; n < 4; ++n)                         \
      _Pragma("unroll") for (int kk = 0; kk < 2; ++kk)                    \
        bfr[n][kk] = *(const bf16x8*)&Bs[cur][(wn + n*16 + fr)*64         \
                                      + (((kk*4 + fq) ^ fr7) * 8)];       \
    asm volatile("s_waitcnt lgkmcnt(0)" ::: "memory");                    \
    SCHED0;                                                               \
    SBAR; SCHED0;              /* all waves done reading buf[cur] */      \
    if (t + 2 < (NT_)) STAGE(cur, t + 2);                                 \
    __builtin_amdgcn_s_setprio(1);                                        \
    _Pragma("unroll") for (int kk = 0; kk < 2; ++kk)                      \
    _Pragma("unroll") for (int m = 0; m < 4; ++m)                         \
    _Pragma("unroll") for (int n = 0; n < 4; ++n)                         \
      acc[m][n] = __builtin_amdgcn_mfma_f32_16x16x32_bf16(                \
          af[m][kk], bfr[n][kk], acc[m][n], 0, 0, 0);                     \
    __builtin_amdgcn_s_setprio(0);                                        \
    if (t + 2 < (NT_))      { VMW(8); }   /* tile t+1 landed */           \
    else if (t + 1 < (NT_)) { VMW(0); }                                   \
    SBAR; SCHED0;                                                         \
  } } while (0)

// ---------------- GEMM1: h = relu(X_gather @ W1[e]^T + b1[e]) -> bf16 ----------------
__global__ __launch_bounds__(256, 2) void gemm1_kernel(
    const u16* __restrict__ Xb, const u16* __restrict__ W1b,
    const float* __restrict__ b1, const int* __restrict__ slot_token,
    const int* __restrict__ offs, const int* __restrict__ padded,
    u16* __restrict__ Hb)
{
  const int h   = blockIdx.x + 32 * (blockIdx.y + 64 * blockIdx.z);  // grid (32,64,8)
  const int e   = h & 7;          // XCD id == expert
  const int r   = h >> 3;
  const int mi  = r >> 5;         // m-tile [0,64)
  const int nti = r & 31;         // n-tile fastest within XCD
  if (mi * 128 >= padded[e]) return;
  const int base_slot = offs[e] + mi * 128;
  const int n0 = nti * 128;
  const int NT = DDIM / 64;       // 16

  __shared__ __align__(16) u16 As[2][8192];
  __shared__ __align__(16) u16 Bs[2][8192];
  __shared__ int toks[128];

  const int tid = threadIdx.x;
  if (tid < 128) toks[tid] = slot_token[base_slot + tid];
  __syncthreads();

  // staging: thread covers rows {g*32 + tid>>3}, pre-swizzled source column
  const int srow = tid >> 3;
  const int scol = ((tid & 7) ^ (srow & 7)) * 8;
  const int sdst = tid * 8;
  const u16* pAg[4];
  const u16* pBg[4];
#pragma unroll
  for (int g = 0; g < 4; ++g) {
    int rr = g * 32 + srow;
    pAg[g] = Xb + (size_t)toks[rr] * DDIM + scol;
    pBg[g] = W1b + ((size_t)e * HDIM + (size_t)(n0 + rr)) * DDIM + scol;
  }

  const int wave = tid >> 6, lane = tid & 63;
  const int wm = (wave >> 1) * 64, wn = (wave & 1) * 64;
  const int fr = lane & 15, fq = lane >> 4, fr7 = fr & 7;

  f32x4 acc[4][4];
#pragma unroll
  for (int m = 0; m < 4; ++m)
#pragma unroll
    for (int n = 0; n < 4; ++n) acc[m][n] = f32x4{0.f, 0.f, 0.f, 0.f};

  GEMM_BODY(NT);

  // epilogue: bias + relu -> bf16
#pragma unroll
  for (int n = 0; n < 4; ++n) {
    int col = n0 + wn + n * 16 + fr;
    float bias = b1[e * HDIM + col];
#pragma unroll
    for (int m = 0; m < 4; ++m) {
      int row0 = wm + m * 16 + fq * 4;
#pragma unroll
      for (int j = 0; j < 4; ++j) {
        float v = acc[m][n][j] + bias;
        v = v > 0.f ? v : 0.f;
        Hb[(size_t)(base_slot + row0 + j) * HDIM + col] = f2bf(v);
      }
    }
  }
}

// ---------------- GEMM2: p = gate*exp(relu(H @ W2[e]^T + b2[e])), atomic add ----------------
__global__ __launch_bounds__(256, 2) void gemm2_kernel(
    const u16* __restrict__ Hb, const u16* __restrict__ W2b,
    const float* __restrict__ b2, const float* __restrict__ slot_gate,
    const int* __restrict__ slot_token, const int* __restrict__ offs,
    const int* __restrict__ padded, float* __restrict__ out)
{
  const int h   = blockIdx.x + 8 * (blockIdx.y + 64 * blockIdx.z);  // grid (8,64,8)
  const int e   = h & 7;
  const int r   = h >> 3;
  const int mi  = r >> 3;         // m-tile [0,64)
  const int nti = r & 7;          // n-tile fastest within XCD
  if (mi * 128 >= padded[e]) return;
  const int base_slot = offs[e] + mi * 128;
  const int n0 = nti * 128;
  const int NT = HDIM / 64;       // 64

  __shared__ __align__(16) u16 As[2][8192];
  __shared__ __align__(16) u16 Bs[2][8192];
  __shared__ int   toks[128];
  __shared__ float gts[128];

  const int tid = threadIdx.x;
  if (tid < 128) {
    toks[tid] = slot_token[base_slot + tid];
    gts[tid]  = slot_gate[base_slot + tid];
  }
  __syncthreads();

  const int srow = tid >> 3;
  const int scol = ((tid & 7) ^ (srow & 7)) * 8;
  const int sdst = tid * 8;
  const u16* pAg[4];
  const u16* pBg[4];
#pragma unroll
  for (int g = 0; g < 4; ++g) {
    int rr = g * 32 + srow;
    pAg[g] = Hb + (size_t)(base_slot + rr) * HDIM + scol;
    pBg[g] = W2b + ((size_t)e * DDIM + (size_t)(n0 + rr)) * HDIM + scol;
  }

  const int wave = tid >> 6, lane = tid & 63;
  const int wm = (wave >> 1) * 64, wn = (wave & 1) * 64;
  const int fr = lane & 15, fq = lane >> 4, fr7 = fr & 7;

  f32x4 acc[4][4];
#pragma unroll
  for (int m = 0; m < 4; ++m)
#pragma unroll
    for (int n = 0; n < 4; ++n) acc[m][n] = f32x4{0.f, 0.f, 0.f, 0.f};

  GEMM_BODY(NT);

  // epilogue: bias + relu -> gate*exp -> atomic add
#pragma unroll
  for (int n = 0; n < 4; ++n) {
    int col = n0 + wn + n * 16 + fr;
    float bias = b2[e * DDIM + col];
#pragma unroll
    for (int m = 0; m < 4; ++m) {
      int row0 = wm + m * 16 + fq * 4;
#pragma unroll
      for (int j = 0; j < 4; ++j) {
        int row = row0 + j;
        float v = acc[m][n][j] + bias;
        v = v > 0.f ? v : 0.f;
        float p = gts[row] * __expf(v);
        atomicAdd(&out[(size_t)toks[row] * DDIM + col], p);
      }
    }
  }
}

// ---------------- final: out = log(out + eps), in place ----------------
__global__ __launch_bounds__(256) void log_kernel(float4* __restrict__ out, int n4) {
  const float EPS = 2.220446049250313e-16f;
  for (int i = blockIdx.x * 256 + threadIdx.x; i < n4; i += gridDim.x * 256) {
    float4 v = out[i];
    v.x = logf(v.x + EPS);
    v.y = logf(v.y + EPS);
    v.z = logf(v.z + EPS);
    v.w = logf(v.w + EPS);
    out[i] = v;
  }
}

extern "C" void kernel_launch(void* const* d_in, const int* in_sizes, int n_in,
                              void* d_out, int out_size, void* d_ws, size_t ws_size,
                              hipStream_t stream)
{
  const float* inp = (const float*)d_in[0];
  const float* gw  = (const float*)d_in[1];
  const float* gb  = (const float*)d_in[2];
  const float* W1  = (const float*)d_in[3];
  const float* b1  = (const float*)d_in[4];
  const float* W2  = (const float*)d_in[5];
  const float* b2  = (const float*)d_in[6];
  float* out = (float*)d_out;

  char* ws = (char*)d_ws;
  size_t off = 0;
  auto alloc = [&](size_t bytes) {
    void* p = ws + off;
    off = (off + bytes + 255) & ~(size_t)255;
    return p;
  };
  u16*   Xb  = (u16*)alloc((size_t)B_TOK * DDIM * 2);
  u16*   W1b = (u16*)alloc((size_t)NEXP * HDIM * DDIM * 2);
  u16*   W2b = (u16*)alloc((size_t)NEXP * DDIM * HDIM * 2);
  u16*   Hb  = (u16*)alloc((size_t)CAP * HDIM * 2);
  int*   slot_token = (int*)alloc(CAP * 4);
  float* slot_gate  = (float*)alloc(CAP * 4);
  int*   tok_e = (int*)alloc(B_TOK * 2 * 4);
  float* tok_g = (float*)alloc(B_TOK * 2 * 4);
  int*   counts  = (int*)alloc(32);
  int*   offs    = (int*)alloc(32);
  int*   padded  = (int*)alloc(32);
  int*   cursors = (int*)alloc(32);

  (void)hipMemsetAsync(counts, 0, 32, stream);
  (void)hipMemsetAsync(cursors, 0, 32, stream);
  (void)hipMemsetAsync(slot_token, 0, CAP * 4, stream);
  (void)hipMemsetAsync(slot_gate, 0, CAP * 4, stream);
  (void)hipMemsetAsync(out, 0, (size_t)out_size * 4, stream);

  cvt_kernel<<<2048, 256, 0, stream>>>((const float4*)inp, (ushort4*)Xb, B_TOK * DDIM / 4);
  cvt_kernel<<<2048, 256, 0, stream>>>((const float4*)W1, (ushort4*)W1b, NEXP * HDIM * DDIM / 4);
  cvt_kernel<<<2048, 256, 0, stream>>>((const float4*)W2, (ushort4*)W2b, NEXP * DDIM * HDIM / 4);

  gate_kernel<<<B_TOK / 4, 256, 0, stream>>>(inp, gw, gb, tok_e, tok_g, counts);
  scan_kernel<<<1, 64, 0, stream>>>(counts, offs, padded);
  scatter_kernel<<<B_TOK / 256, 256, 0, stream>>>(tok_e, tok_g, offs, cursors,
                                                  slot_token, slot_gate);

  gemm1_kernel<<<dim3(32, 64, NEXP), 256, 0, stream>>>(
      Xb, W1b, b1, slot_token, offs, padded, Hb);
  gemm2_kernel<<<dim3(8, 64, NEXP), 256, 0, stream>>>(
      Hb, W2b, b2, slot_gate, slot_token, offs, padded, out);

  log_kernel<<<2048, 256, 0, stream>>>((float4*)out, out_size / 4);
}